// Round 11
// baseline (10.184 us; speedup 1.0000x reference)
//
#include <hip/hip_runtime.h>
#include <hip/hip_bf16.h>

// FWHT for 12 qubits (N=4096), batch 256, real/imag planes.
// out = FWHT(x) / 64  (H = (H2)^{⊗12}, entries ±1/64; H is never read).
//
// CONCURRENT groups: 512 threads/block, one block per batch (grid 256).
// Threads [0,256) transform the real vector, [256,512) the imag vector,
// each group running the proven radix-16 / pad-17 body on its own LDS
// array. Both groups execute the identical phase structure, so the two
// shared __syncthreads align naturally. Critical path = load + 3 rounds
// + store (half of the sequential R4 pipeline); 8 waves/CU (2/SIMD).
//
// Radix-16 rounds over bits [3:0], [7:4], [11:8]; pad n->(n>>4)*17+(n&15)
// (proven conflict-free b32 pattern).

#define NN 4096
#define T  512
#define PAD (NN + NN / 16)                  // 4352 floats = 17 KiB

__device__ __forceinline__ void fwht16(float x[16]) {
#pragma unroll
    for (int s = 0; s < 4; ++s) {
        const int st = 1 << s;
#pragma unroll
        for (int i = 0; i < 16; ++i) {
            if ((i & st) == 0) {
                const float a = x[i];
                const float b = x[i + st];
                x[i]      = a + b;
                x[i + st] = a - b;
            }
        }
    }
}

__global__ __launch_bounds__(T)
void fwht_kernel(const float* __restrict__ gr,
                 const float* __restrict__ gi,
                 float* __restrict__ out) {
    __shared__ float sm[2 * PAD];           // 34 KiB, one array per group

    const int b = blockIdx.x;               // batch 0..255
    const int u = threadIdx.x;              // 0..511
    const int g = u >> 8;                   // 0 = real, 1 = imag
    const int t = u & 255;                  // index within group

    const float* src = (g == 0) ? (gr + (size_t)b * NN)
                                : (gi + (size_t)b * NN);
    float* dst = out + (size_t)(g * 256 + b) * NN;
    float* s   = sm + g * PAD;

    const int baseB = (t >> 4) * 272 + (t & 15);   // bits [7:4] gather
    const int baseC = (t >> 4) * 17 + (t & 15);    // bits [11:8] gather
    const float sc = 0.015625f;                    // (1/sqrt(2))^12

    // ---- load: 4x dwordx4/thread, fully coalesced ----
    float x[16];
    const float4* p4 = (const float4*)(src + t * 16);
#pragma unroll
    for (int k = 0; k < 4; ++k) {
        const float4 v = p4[k];
        x[4 * k + 0] = v.x; x[4 * k + 1] = v.y;
        x[4 * k + 2] = v.z; x[4 * k + 3] = v.w;
    }

    // ---- Round A: bits [3:0] (thread t owns n = t*16 + r) ----
    fwht16(x);
#pragma unroll
    for (int r = 0; r < 16; ++r) s[t * 17 + r] = x[r];
    __syncthreads();                        // bar1 (both groups aligned)

    // ---- Round B: bits [7:4]; thread = (P = t>>4, R = t&15) ----
#pragma unroll
    for (int q = 0; q < 16; ++q) x[q] = s[baseB + q * 17];
    fwht16(x);
#pragma unroll
    for (int q = 0; q < 16; ++q) s[baseB + q * 17] = x[q];   // same addrs
    __syncthreads();                        // bar2

    // ---- Round C: bits [11:8]; thread = (Q = t>>4, R = t&15) ----
#pragma unroll
    for (int p = 0; p < 16; ++p) x[p] = s[baseC + p * 272];
    fwht16(x);

    // ---- scale 1/64, store (1 KiB contiguous per wave-instr) ----
#pragma unroll
    for (int p = 0; p < 16; ++p) dst[p * 256 + t] = x[p] * sc;
}

extern "C" void kernel_launch(void* const* d_in, const int* in_sizes, int n_in,
                              void* d_out, int out_size, void* d_ws, size_t ws_size,
                              hipStream_t stream) {
    const float* gr = (const float*)d_in[0];
    const float* gi = (const float*)d_in[1];
    float* out = (float*)d_out;

    fwht_kernel<<<256, T, 0, stream>>>(gr, gi, out);
}

// Round 12
// 10.170 us; speedup vs baseline: 1.0014x; 1.0014x over previous
//
#include <hip/hip_runtime.h>
#include <hip/hip_bf16.h>

// FWHT for 12 qubits (N=4096), batch 256, real/imag planes.
// out = FWHT(x) / 64  (H = (H2)^{⊗12}, entries ±1/64; H is never read).
//
// Best-measured variant (R4: 9.90us). Radix-16: three rounds of
// in-register FWHT-16 over bit-groups [3:0], [7:4], [11:8], two
// padded-LDS exchanges (pad: n -> (n>>4)*17 + (n&15), stride-17 rows,
// all phases <=2 lanes/bank = free).
//
// Each block processes BOTH vectors of one batch (real then imag),
// sequentially. All 8 dwordx4 loads issue at kernel entry; v2's memory
// latency hides under v1's compute, v1's stores drain under v2's
// compute. Grid 256 = 1 block/CU, 4 waves.
//
// Four structurally independent schedules (sequential / skewed /
// barrier-reduced / concurrent-groups) all measure 9.9-10.2us: the
// residual above the ~2.7us BW floor is fixed dispatch + latency ramp,
// not kernel structure.

#define NN 4096
#define T  256

__device__ __forceinline__ void fwht16(float x[16]) {
#pragma unroll
    for (int s = 0; s < 4; ++s) {
        const int st = 1 << s;
#pragma unroll
        for (int i = 0; i < 16; ++i) {
            if ((i & st) == 0) {
                const float a = x[i];
                const float b = x[i + st];
                x[i]      = a + b;
                x[i + st] = a - b;
            }
        }
    }
}

// Three rounds + scaled store for one 4096-vector. Leaves LDS dirty;
// caller must __syncthreads() before reusing s.
__device__ __forceinline__ void fwht4096(float x[16], float* s, int t,
                                         float* __restrict__ dst) {
    // ---- Round A: bits [3:0] ----
    fwht16(x);
#pragma unroll
    for (int r = 0; r < 16; ++r)
        s[t * 17 + r] = x[r];
    __syncthreads();

    // ---- Round B: bits [7:4]; thread = (P = t>>4, R = t&15) ----
    const int baseB = (t >> 4) * 272 + (t & 15);
#pragma unroll
    for (int q = 0; q < 16; ++q) x[q] = s[baseB + q * 17];
    fwht16(x);
#pragma unroll
    for (int q = 0; q < 16; ++q) s[baseB + q * 17] = x[q];  // same addrs
    __syncthreads();

    // ---- Round C: bits [11:8]; thread = (Q = t>>4, R = t&15) ----
    const int baseC = (t >> 4) * 17 + (t & 15);
#pragma unroll
    for (int p = 0; p < 16; ++p) x[p] = s[baseC + p * 272];
    fwht16(x);

    const float scale = 0.015625f;          // (1/sqrt(2))^12
#pragma unroll
    for (int p = 0; p < 16; ++p)
        dst[p * 256 + t] = x[p] * scale;    // 1 KiB contiguous per instr
}

__global__ __launch_bounds__(T)
void fwht_kernel(const float* __restrict__ xr,
                 const float* __restrict__ xi,
                 float* __restrict__ out) {
    __shared__ float s[NN + NN / 16];       // 4352 floats = 17 KiB

    const int b = blockIdx.x;               // batch 0..255
    const int t = threadIdx.x;              // 0..255

    // Issue ALL loads for both vectors up front (8x dwordx4/thread).
    const float4* p1 = (const float4*)(xr + (size_t)b * NN + t * 16);
    const float4* p2 = (const float4*)(xi + (size_t)b * NN + t * 16);
    const float4 a0 = p1[0], a1 = p1[1], a2 = p1[2], a3 = p1[3];
    const float4 b0 = p2[0], b1 = p2[1], b2 = p2[2], b3 = p2[3];

    // ---- vector 1: real ----
    float x[16];
    x[0]  = a0.x; x[1]  = a0.y; x[2]  = a0.z; x[3]  = a0.w;
    x[4]  = a1.x; x[5]  = a1.y; x[6]  = a1.z; x[7]  = a1.w;
    x[8]  = a2.x; x[9]  = a2.y; x[10] = a2.z; x[11] = a2.w;
    x[12] = a3.x; x[13] = a3.y; x[14] = a3.z; x[15] = a3.w;
    fwht4096(x, s, t, out + (size_t)b * NN);

    __syncthreads();                        // round-C reads done before reuse

    // ---- vector 2: imag (loads arrived long ago) ----
    float y[16];
    y[0]  = b0.x; y[1]  = b0.y; y[2]  = b0.z; y[3]  = b0.w;
    y[4]  = b1.x; y[5]  = b1.y; y[6]  = b1.z; y[7]  = b1.w;
    y[8]  = b2.x; y[9]  = b2.y; y[10] = b2.z; y[11] = b2.w;
    y[12] = b3.x; y[13] = b3.y; y[14] = b3.z; y[15] = b3.w;
    fwht4096(y, s, t, out + (size_t)(256 + b) * NN);
}

extern "C" void kernel_launch(void* const* d_in, const int* in_sizes, int n_in,
                              void* d_out, int out_size, void* d_ws, size_t ws_size,
                              hipStream_t stream) {
    const float* xr = (const float*)d_in[0];
    const float* xi = (const float*)d_in[1];
    float* out = (float*)d_out;

    fwht_kernel<<<256, T, 0, stream>>>(xr, xi, out);
}